// Round 3
// baseline (606.626 us; speedup 1.0000x reference)
//
#include <hip/hip_runtime.h>
#include <hip/hip_bf16.h>
#include <cstdint>
#include <cstddef>

// Problem constants
#define D_    1024
#define H_    16
#define HD_   64
#define S_    4
#define B_    8
#define L_    2048
#define HID_  4096
#define EPS_  1e-6f
#define SCALE_ 0.125f   // 1/sqrt(HD)

#define TILE_  4        // rows staged per LDS tile in main kernel

// ---------------- workspace layout (bytes) ----------------
// pacc is LAST so its size can adapt to ws_size via NC in {16,4,1}.
static constexpr size_t LEN_OFF   = 0;                                  // 32 x int
static constexpr size_t QBUF_OFF  = 256;                                // [8][1024] f32
static constexpr size_t QWF_OFF   = QBUF_OFF  + (size_t)B_*D_*4;        // [8][16][1024] f32
static constexpr size_t QBIAS_OFF = QWF_OFF   + (size_t)B_*H_*D_*4;     // [8][16] f32
static constexpr size_t PM_OFF    = QBIAS_OFF + 1024;                   // [<=512][16] f32
static constexpr size_t PDEN_OFF  = PM_OFF    + (size_t)512*H_*4;       // [<=512][16] f32
static constexpr size_t CTXD_OFF  = PDEN_OFF  + (size_t)512*H_*4;       // [32][16][1024] f32
static constexpr size_t ABAR_OFF  = CTXD_OFF  + (size_t)32*H_*D_*4;     // [8][1024]
static constexpr size_t SEQC_OFF  = ABAR_OFF  + (size_t)B_*D_*4;        // [8][1024]
static constexpr size_t CTXB_OFF  = SEQC_OFF  + (size_t)B_*D_*4;        // [8][1024]
static constexpr size_t GACT_OFF  = CTXB_OFF  + (size_t)B_*D_*4;        // [8][4096]
static constexpr size_t PACC_OFF  = GACT_OFF  + (size_t)B_*HID_*4;      // [32*NC][16][1024] f32
static constexpr size_t ws_need(int nc) { return PACC_OFF + (size_t)32*nc*H_*D_*4; }

// ---------------- helpers ----------------
__device__ __forceinline__ float wred64(float v) {
  v += __shfl_xor(v, 32); v += __shfl_xor(v, 16); v += __shfl_xor(v, 8);
  v += __shfl_xor(v, 4);  v += __shfl_xor(v, 2);  v += __shfl_xor(v, 1);
  return v;
}
__device__ __forceinline__ int wred64i(int v) {
  v += __shfl_xor(v, 32); v += __shfl_xor(v, 16); v += __shfl_xor(v, 8);
  v += __shfl_xor(v, 4);  v += __shfl_xor(v, 2);  v += __shfl_xor(v, 1);
  return v;
}
__device__ __forceinline__ float dot4(const float4 a, const float4 b) {
  return a.x*b.x + a.y*b.y + a.z*b.z + a.w*b.w;
}
__device__ __forceinline__ void fma4(float4& a, float s, const float4& v) {
  a.x = fmaf(s, v.x, a.x); a.y = fmaf(s, v.y, a.y);
  a.z = fmaf(s, v.z, a.z); a.w = fmaf(s, v.w, a.w);
}
__device__ __forceinline__ void scale_fma4(float4& a, float f, float s, const float4& v) {
  a.x = fmaf(s, v.x, a.x*f); a.y = fmaf(s, v.y, a.y*f);
  a.z = fmaf(s, v.z, a.z*f); a.w = fmaf(s, v.w, a.w*f);
}
__device__ __forceinline__ float sigmoidf_(float x) { return 1.0f / (1.0f + __expf(-x)); }

#define NEG_BIG -1.0e30f

// online-softmax accumulate of one (row, head); s/m/den wave-uniform (post-wred64)
__device__ __forceinline__ void online_upd(float s, float rfac, const float4* rv,
                                           float& m, float& den, float4* acc) {
  if (s <= m) {
    float p = __expf(s - m); den += p; float w = p * rfac;
    #pragma unroll
    for (int q = 0; q < 4; ++q) fma4(acc[q], w, rv[q]);
  } else {
    float f = __expf(m - s); den = fmaf(den, f, 1.0f);
    #pragma unroll
    for (int q = 0; q < 4; ++q) scale_fma4(acc[q], f, rfac, rv[q]);
    m = s;
  }
}

// ---------------- K0a: ragged lengths from masks (robust to int32 or uint8 layout) --------
__global__ __launch_bounds__(256) void k_lengths(const int* __restrict__ masks,
                                                 int* __restrict__ lengths) {
  int sb = blockIdx.x;            // 32
  int tid = threadIdx.x;
  // probe: packed-uint8 bool layout gives int words > 1 (mask is a 0-run then 1-run,
  // so any row with padding contains a word like 0x01010100). Scan 64KB (safe under
  // both layouts: uint8 total = 64KB, int32 total = 256KB).
  int flag = 0;
  for (int i = tid; i < (S_*B_*L_)/4; i += 256) {
    unsigned v = ((const unsigned*)masks)[i];
    if (v > 1u) flag = 1;
  }
  flag = wred64i(flag);
  __shared__ int sf[4];
  if ((tid & 63) == 0) sf[tid >> 6] = flag;
  __syncthreads();
  int packed = sf[0] | sf[1] | sf[2] | sf[3];
  int cnt = 0;
  if (packed) {
    const unsigned char* m = (const unsigned char*)masks + (size_t)sb * L_;
    for (int l = tid; l < L_; l += 256) cnt += (m[l] == 0) ? 1 : 0;
  } else {
    const int* m = masks + (size_t)sb * L_;
    for (int l = tid; l < L_; l += 256) cnt += (m[l] == 0) ? 1 : 0;
  }
  cnt = wred64i(cnt);
  __shared__ int sr[4];
  if ((tid & 63) == 0) sr[tid >> 6] = cnt;
  __syncthreads();
  if (tid == 0) lengths[sb] = sr[0] + sr[1] + sr[2] + sr[3];
}

// ---------------- K0b: fused rmsnorm(context)+q-projection; 1 col/wave, grid 256 --------
__global__ __launch_bounds__(256) void k_qproj(const float* __restrict__ ipw,
                                               const float* __restrict__ ipb,
                                               const float* __restrict__ context,
                                               const float* __restrict__ qnw,
                                               float* __restrict__ qbuf) {
  __shared__ float xs[B_ * D_];
  __shared__ float rfs[B_];
  int tid = threadIdx.x, wave = tid >> 6, lane = tid & 63;
  for (int i = tid; i < B_*D_/4; i += 256) ((float4*)xs)[i] = ((const float4*)context)[i];
  __syncthreads();
  #pragma unroll
  for (int rep = 0; rep < 2; ++rep) {          // wave w handles rows w and w+4
    int b = wave + rep * 4;
    float ss = 0.f;
    #pragma unroll
    for (int j = 0; j < 4; ++j) {
      float4 v = ((const float4*)xs)[b*256 + lane + j*64];
      ss += dot4(v, v);
    }
    ss = wred64(ss);
    if (lane == 0) rfs[b] = rsqrtf(ss * (1.0f / D_) + EPS_);
  }
  __syncthreads();
  for (int i = tid; i < B_*D_/4; i += 256) {
    int b = i >> 8, d4 = i & 255;
    float4 v = ((float4*)xs)[i];
    float4 w = ((const float4*)qnw)[d4];
    float r = rfs[b];
    ((float4*)xs)[i] = make_float4(v.x*r*w.x, v.y*r*w.y, v.z*r*w.z, v.w*r*w.w);
  }
  __syncthreads();
  int col = blockIdx.x * 4 + wave;             // grid 256 -> 1024 cols
  const float4* wr = (const float4*)(ipw + (size_t)col * D_);
  float p[8] = {0,0,0,0,0,0,0,0};
  for (int it = 0; it < 4; ++it) {
    float4 w = wr[lane + it*64];
    #pragma unroll
    for (int b = 0; b < 8; ++b)
      p[b] += dot4(w, ((const float4*)xs)[b*256 + lane + it*64]);
  }
  #pragma unroll
  for (int b = 0; b < 8; ++b) {
    float v = wred64(p[b]);
    if (lane == 0) qbuf[(size_t)b * D_ + col] = v + ipb[col];
  }
}

// ---------------- K0c: qwf[b,h,d] = scale*snw[d]*sum_hd q[b,h,hd]*wk[h*64+hd,d]; qbias ---
__global__ __launch_bounds__(256) void k_qwf(const float* __restrict__ ipw,
                                             const float* __restrict__ ipb,
                                             const float* __restrict__ snw,
                                             const float* __restrict__ qbuf,
                                             float* __restrict__ qwf,
                                             float* __restrict__ qbias) {
  int bid = blockIdx.x;            // 128 = B*H
  int b = bid >> 4, h = bid & 15;
  int tid = threadIdx.x;
  __shared__ float qs[64];
  if (tid < 64) qs[tid] = qbuf[(size_t)b * D_ + h*64 + tid];
  __syncthreads();
  float acc[4] = {0,0,0,0};
  const float* wk = ipw + (size_t)(D_ + h*64) * D_;
  for (int hd = 0; hd < 64; ++hd) {
    float qv = qs[hd];
    const float* row = wk + (size_t)hd * D_;
    #pragma unroll
    for (int k = 0; k < 4; ++k) acc[k] = fmaf(qv, row[tid + k*256], acc[k]);
  }
  float* out = qwf + ((size_t)b * H_ + h) * D_;
  #pragma unroll
  for (int k = 0; k < 4; ++k) out[tid + k*256] = acc[k] * SCALE_ * snw[tid + k*256];
  if (tid == 0) {
    float s = 0.f;
    for (int hd = 0; hd < 64; ++hd) s += qs[hd] * ipb[D_ + h*64 + hd];
    qbias[b * H_ + h] = s * SCALE_;
  }
}

// ---------------- K1: main streaming attention (one pass over sequences) ----------------
// grid = 32*NC blocks of 512 threads (8 waves, 2 heads/wave).
// Per chunk: double-buffered 4-row LDS tiles, per-head online softmax, partials to ws.
template <int NC>
__global__ __launch_bounds__(512, 4) void k_attn(
    const float* __restrict__ seqs, const float* __restrict__ qwf,
    const float* __restrict__ qbias, const int* __restrict__ lengths,
    float* __restrict__ pacc, float* __restrict__ pm, float* __restrict__ pden) {
  constexpr int CHUNK = L_ / NC;
  __shared__ float tile[2][TILE_ * D_];   // 32 KB
  int bid = blockIdx.x;
  int sb = bid / NC;
  int c = bid % NC;
  int len = lengths[sb];
  int r0 = c * CHUNK;
  if (r0 >= len) return;                  // reduce kernel skips these slots
  int nrows = min(CHUNK, len - r0);
  int nt = (nrows + TILE_ - 1) / TILE_;
  int tid = threadIdx.x, wave = tid >> 6, lane = tid & 63;
  int b = sb & (B_ - 1);
  int h0 = wave * 2;
  const float* base = seqs + ((size_t)sb * L_ + r0) * D_;

  // qwf fragments for this lane's d-pattern: d = lane*4 + q*256
  const float4* qa4 = (const float4*)(qwf + ((size_t)b * H_ + h0) * D_);
  const float4* qb4 = (const float4*)(qwf + ((size_t)b * H_ + h0 + 1) * D_);
  float4 qwA[4], qwB[4];
  #pragma unroll
  for (int q = 0; q < 4; ++q) { qwA[q] = qa4[lane + q*64]; qwB[q] = qb4[lane + q*64]; }
  float qbA = qbias[b * H_ + h0], qbB = qbias[b * H_ + h0 + 1];

  float4 accA[4], accB[4];
  #pragma unroll
  for (int q = 0; q < 4; ++q) { accA[q] = make_float4(0,0,0,0); accB[q] = make_float4(0,0,0,0); }
  float mA = NEG_BIG, mB = NEG_BIG, dA = 0.f, dB = 0.f;

  // prologue: stage tile 0 (prefetches stay within the chunk: nt*TILE_ <= CHUNK)
  {
    const float4* g = (const float4*)base;
    float4 s0 = g[tid], s1 = g[tid + 512];
    ((float4*)&tile[0][0])[tid] = s0;
    ((float4*)&tile[0][0])[tid + 512] = s1;
  }
  __syncthreads();
  int buf = 0;
  for (int t = 0; t < nt; ++t) {
    bool more = (t + 1 < nt);
    float4 nx0, nx1;
    if (more) {
      const float4* g = (const float4*)(base + (size_t)(t + 1) * TILE_ * D_);
      nx0 = g[tid]; nx1 = g[tid + 512];
    }
    int rmax = min(TILE_, nrows - t * TILE_);
    for (int i = 0; i < rmax; ++i) {
      const float4* rp = (const float4*)&tile[buf][i * D_];
      float4 rv[4];
      #pragma unroll
      for (int q = 0; q < 4; ++q) rv[q] = rp[lane + q*64];
      float ss = 0.f, pA = 0.f, pB = 0.f;
      #pragma unroll
      for (int q = 0; q < 4; ++q) {
        ss += dot4(rv[q], rv[q]); pA += dot4(rv[q], qwA[q]); pB += dot4(rv[q], qwB[q]);
      }
      ss = wred64(ss); pA = wred64(pA); pB = wred64(pB);
      float rf = rsqrtf(ss * (1.0f / D_) + EPS_);
      online_upd(fmaf(rf, pA, qbA), rf, rv, mA, dA, accA);
      online_upd(fmaf(rf, pB, qbB), rf, rv, mB, dB, accB);
    }
    if (more) {
      ((float4*)&tile[buf ^ 1][0])[tid] = nx0;
      ((float4*)&tile[buf ^ 1][0])[tid + 512] = nx1;
    }
    __syncthreads();
    buf ^= 1;
  }
  // write chunk partials
  size_t slot = (size_t)sb * NC + c;
  float4* pa = (float4*)(pacc + (slot * H_ + h0) * D_);
  float4* pb = (float4*)(pacc + (slot * H_ + h0 + 1) * D_);
  #pragma unroll
  for (int q = 0; q < 4; ++q) { pa[lane + q*64] = accA[q]; pb[lane + q*64] = accB[q]; }
  if (lane == 0) {
    pm[slot * H_ + h0] = mA;     pden[slot * H_ + h0] = dA;
    pm[slot * H_ + h0 + 1] = mB; pden[slot * H_ + h0 + 1] = dB;
  }
}

// ---------------- K2: LSE merge of chunk partials -> normalized ctxd[s,b,h,:] ----------
template <int NC>
__global__ __launch_bounds__(256) void k_reduce(const int* __restrict__ lengths,
    const float* __restrict__ pacc, const float* __restrict__ pm,
    const float* __restrict__ pden, float* __restrict__ ctxd) {
  constexpr int CHUNK = L_ / NC;
  int bid = blockIdx.x;            // 512 = 32*16
  int sb = bid >> 4, h = bid & 15;
  int len = lengths[sb];
  int nact = (len + CHUNK - 1) / CHUNK;
  int tid = threadIdx.x;
  float M = NEG_BIG;
  for (int c = 0; c < nact; ++c) M = fmaxf(M, pm[((size_t)sb * NC + c) * H_ + h]);
  float den = 0.f;
  for (int c = 0; c < nact; ++c) {
    size_t s = ((size_t)sb * NC + c) * H_ + h;
    den += pden[s] * __expf(pm[s] - M);
  }
  float inv = 1.0f / den;
  float4 o = make_float4(0,0,0,0);
  for (int c = 0; c < nact; ++c) {
    size_t s = ((size_t)sb * NC + c) * H_ + h;
    float w = __expf(pm[s] - M) * inv;
    float4 v = ((const float4*)(pacc + s * D_))[tid];
    fma4(o, w, v);
  }
  ((float4*)(ctxd + ((size_t)sb * H_ + h) * D_))[tid] = o;
}

// ---------------- K3: abar[b,col] = xs_h . wv[col,:] + bv; 1 col/wave, grid 256 --------
__global__ __launch_bounds__(256) void k_vproj(const float* __restrict__ ipw,
    const float* __restrict__ ipb, const float* __restrict__ snw,
    const float* __restrict__ ctxd, float* __restrict__ abar) {
  __shared__ float xs[B_ * D_];
  int tid = threadIdx.x, wave = tid >> 6, lane = tid & 63;
  int h = blockIdx.x >> 4;                     // 16 blocks per head
  for (int i = tid; i < B_*D_/4; i += 256) {
    int b = i >> 8, d4 = i & 255;
    float4 a = make_float4(0,0,0,0);
    #pragma unroll
    for (int s = 0; s < S_; ++s) {
      float4 v = ((const float4*)(ctxd + (((size_t)(s * B_ + b)) * H_ + h) * D_))[d4];
      a.x += v.x; a.y += v.y; a.z += v.z; a.w += v.w;
    }
    float4 w = ((const float4*)snw)[d4];
    ((float4*)xs)[i] = make_float4(0.25f*a.x*w.x, 0.25f*a.y*w.y, 0.25f*a.z*w.z, 0.25f*a.w*w.w);
  }
  __syncthreads();
  int col = blockIdx.x * 4 + wave;             // grid 256 -> 1024 cols; col/64 == h
  const float4* wr = (const float4*)(ipw + (size_t)(2 * D_ + col) * D_);
  float p[8] = {0,0,0,0,0,0,0,0};
  for (int it = 0; it < 4; ++it) {
    float4 w = wr[lane + it*64];
    #pragma unroll
    for (int b = 0; b < 8; ++b)
      p[b] += dot4(w, ((const float4*)xs)[b*256 + lane + it*64]);
  }
  #pragma unroll
  for (int b = 0; b < 8; ++b) {
    float v = wred64(p[b]);
    if (lane == 0) abar[(size_t)b * D_ + col] = v + ipb[2 * D_ + col];
  }
}

// ---------------- K4: seq_ctx = abar @ out_w.T + out_b; 1 col/wave, grid 256 ----------
__global__ __launch_bounds__(256) void k_outproj(const float* __restrict__ outw,
    const float* __restrict__ outb, const float* __restrict__ abar,
    float* __restrict__ seqctx) {
  __shared__ float xs[B_ * D_];
  int tid = threadIdx.x, wave = tid >> 6, lane = tid & 63;
  for (int i = tid; i < B_*D_/4; i += 256) ((float4*)xs)[i] = ((const float4*)abar)[i];
  __syncthreads();
  int col = blockIdx.x * 4 + wave;             // grid 256
  const float4* wr = (const float4*)(outw + (size_t)col * D_);
  float p[8] = {0,0,0,0,0,0,0,0};
  for (int it = 0; it < 4; ++it) {
    float4 w = wr[lane + it*64];
    #pragma unroll
    for (int b = 0; b < 8; ++b)
      p[b] += dot4(w, ((const float4*)xs)[b*256 + lane + it*64]);
  }
  #pragma unroll
  for (int b = 0; b < 8; ++b) {
    float v = wred64(p[b]);
    if (lane == 0) seqctx[(size_t)b * D_ + col] = v + outb[col];
  }
}

// ---------------- K5: sigmoid gate + residual; 1 col/wave, grid 256 ----------
__global__ __launch_bounds__(256) void k_gate(const float* __restrict__ gw,
    const float* __restrict__ gb, const float* __restrict__ context,
    const float* __restrict__ seqctx, float* __restrict__ ctxbuf) {
  __shared__ float xs[B_ * 2 * D_];  // 64 KB: [b][0..1023]=context, [1024..2047]=seq_ctx
  int tid = threadIdx.x, wave = tid >> 6, lane = tid & 63;
  for (int i = tid; i < B_*2*D_/4; i += 256) {
    int b = i >> 9, j4 = i & 511;
    float4 v = (j4 < 256) ? ((const float4*)(context + (size_t)b * D_))[j4]
                          : ((const float4*)(seqctx + (size_t)b * D_))[j4 - 256];
    ((float4*)xs)[i] = v;
  }
  __syncthreads();
  int col = blockIdx.x * 4 + wave;             // grid 256
  const float4* wr = (const float4*)(gw + (size_t)col * 2 * D_);
  float p[8] = {0,0,0,0,0,0,0,0};
  for (int it = 0; it < 8; ++it) {
    float4 w = wr[lane + it*64];
    #pragma unroll
    for (int b = 0; b < 8; ++b)
      p[b] += dot4(w, ((const float4*)xs)[b*512 + lane + it*64]);
  }
  #pragma unroll
  for (int b = 0; b < 8; ++b) {
    float v = wred64(p[b]);
    if (lane == 0) {
      float g = sigmoidf_(v + gb[col]);
      float cv = context[(size_t)b * D_ + col];
      float sv = seqctx[(size_t)b * D_ + col];
      ctxbuf[(size_t)b * D_ + col] = fmaf(g, sv, cv);
    }
  }
}

// ---------------- K6: fused rmsnorm(ctx)+SwiGLU gate/up; 1 col/wave, grid 1024 ----------
__global__ __launch_bounds__(256) void k_gateup(const float* __restrict__ gup,
    const float* __restrict__ gub, const float* __restrict__ ctxbuf,
    const float* __restrict__ fnw, float* __restrict__ gact) {
  __shared__ float xs[B_ * D_];
  __shared__ float rfs[B_];
  int tid = threadIdx.x, wave = tid >> 6, lane = tid & 63;
  for (int i = tid; i < B_*D_/4; i += 256) ((float4*)xs)[i] = ((const float4*)ctxbuf)[i];
  __syncthreads();
  #pragma unroll
  for (int rep = 0; rep < 2; ++rep) {          // wave w handles rows w and w+4
    int b = wave + rep * 4;
    float ss = 0.f;
    #pragma unroll
    for (int j = 0; j < 4; ++j) {
      float4 v = ((const float4*)xs)[b*256 + lane + j*64];
      ss += dot4(v, v);
    }
    ss = wred64(ss);
    if (lane == 0) rfs[b] = rsqrtf(ss * (1.0f / D_) + EPS_);
  }
  __syncthreads();
  for (int i = tid; i < B_*D_/4; i += 256) {
    int b = i >> 8, d4 = i & 255;
    float4 v = ((float4*)xs)[i];
    float4 w = ((const float4*)fnw)[d4];
    float r = rfs[b];
    ((float4*)xs)[i] = make_float4(v.x*r*w.x, v.y*r*w.y, v.z*r*w.z, v.w*r*w.w);
  }
  __syncthreads();
  int col = blockIdx.x * 4 + wave;             // grid 1024 -> 4096 cols
  const float4* wg = (const float4*)(gup + (size_t)col * D_);
  const float4* wv = (const float4*)(gup + (size_t)(HID_ + col) * D_);
  float pg[8] = {0,0,0,0,0,0,0,0};
  float pv[8] = {0,0,0,0,0,0,0,0};
  for (int it = 0; it < 4; ++it) {
    float4 a = wg[lane + it*64];
    float4 c = wv[lane + it*64];
    #pragma unroll
    for (int b = 0; b < 8; ++b) {
      float4 x = ((const float4*)xs)[b*256 + lane + it*64];
      pg[b] += dot4(a, x);
      pv[b] += dot4(c, x);
    }
  }
  #pragma unroll
  for (int b = 0; b < 8; ++b) {
    float g = wred64(pg[b]);
    float v = wred64(pv[b]);
    if (lane == 0) {
      g += gub[col]; v += gub[HID_ + col];
      gact[(size_t)b * HID_ + col] = g * sigmoidf_(g) * v;
    }
  }
}

// ---------------- K7: out = ctx + gact @ down_w.T + down_b; 1 col/wave, grid 256 --------
__global__ __launch_bounds__(256) void k_down(const float* __restrict__ dw,
    const float* __restrict__ db, const float* __restrict__ gact,
    const float* __restrict__ ctxbuf, float* __restrict__ out) {
  __shared__ float xs[B_ * 2048];   // 64 KB, staged in two halves of IN=4096
  int tid = threadIdx.x, wave = tid >> 6, lane = tid & 63;
  int col = blockIdx.x * 4 + wave;             // grid 256
  float p[8] = {0,0,0,0,0,0,0,0};
  for (int ph = 0; ph < 2; ++ph) {
    __syncthreads();
    for (int i = tid; i < B_*2048/4; i += 256) {
      int b = i >> 9, j4 = i & 511;
      ((float4*)xs)[i] = ((const float4*)(gact + (size_t)b * HID_ + ph * 2048))[j4];
    }
    __syncthreads();
    const float4* wr = (const float4*)(dw + (size_t)col * HID_ + ph * 2048);
    for (int it = 0; it < 8; ++it) {
      float4 w = wr[lane + it*64];
      #pragma unroll
      for (int b = 0; b < 8; ++b)
        p[b] += dot4(w, ((const float4*)xs)[b*512 + lane + it*64]);
    }
  }
  #pragma unroll
  for (int b = 0; b < 8; ++b) {
    float v = wred64(p[b]);
    if (lane == 0)
      out[(size_t)b * D_ + col] = ctxbuf[(size_t)b * D_ + col] + v + db[col];
  }
}

// ---------------- host launcher ----------------
extern "C" void kernel_launch(void* const* d_in, const int* in_sizes, int n_in,
                              void* d_out, int out_size, void* d_ws, size_t ws_size,
                              hipStream_t stream) {
  (void)in_sizes; (void)n_in; (void)out_size;

  const float* context = (const float*)d_in[0];
  const float* seqs    = (const float*)d_in[1];
  const float* qnw     = (const float*)d_in[2];
  const float* snw     = (const float*)d_in[3];
  const float* ipw     = (const float*)d_in[4];
  const float* ipb     = (const float*)d_in[5];
  const float* outw    = (const float*)d_in[6];
  const float* outb    = (const float*)d_in[7];
  const float* gw      = (const float*)d_in[8];
  const float* gb      = (const float*)d_in[9];
  const float* fnw     = (const float*)d_in[10];
  const float* gup     = (const float*)d_in[11];
  const float* gub     = (const float*)d_in[12];
  const float* dw      = (const float*)d_in[13];
  const float* db      = (const float*)d_in[14];
  const int*   masks   = (const int*)d_in[15];
  float* out = (float*)d_out;

  char* ws = (char*)d_ws;
  int*   lengths = (int*)(ws + LEN_OFF);
  float* qbuf    = (float*)(ws + QBUF_OFF);
  float* qwf     = (float*)(ws + QWF_OFF);
  float* qbias   = (float*)(ws + QBIAS_OFF);
  float* pm      = (float*)(ws + PM_OFF);
  float* pden    = (float*)(ws + PDEN_OFF);
  float* ctxd    = (float*)(ws + CTXD_OFF);
  float* abar    = (float*)(ws + ABAR_OFF);
  float* seqctx  = (float*)(ws + SEQC_OFF);
  float* ctxbuf  = (float*)(ws + CTXB_OFF);
  float* gact    = (float*)(ws + GACT_OFF);
  float* pacc    = (float*)(ws + PACC_OFF);

  k_lengths<<<dim3(32),  dim3(256), 0, stream>>>(masks, lengths);
  k_qproj  <<<dim3(256), dim3(256), 0, stream>>>(ipw, ipb, context, qnw, qbuf);
  k_qwf    <<<dim3(128), dim3(256), 0, stream>>>(ipw, ipb, snw, qbuf, qwf, qbias);

  // NC adapts to available scratch (branch is stable across calls -> graph-safe)
  if (ws_size >= ws_need(16)) {
    k_attn<16>  <<<dim3(32 * 16), dim3(512), 0, stream>>>(seqs, qwf, qbias, lengths,
                                                          pacc, pm, pden);
    k_reduce<16><<<dim3(512), dim3(256), 0, stream>>>(lengths, pacc, pm, pden, ctxd);
  } else if (ws_size >= ws_need(4)) {
    k_attn<4>   <<<dim3(32 * 4), dim3(512), 0, stream>>>(seqs, qwf, qbias, lengths,
                                                         pacc, pm, pden);
    k_reduce<4> <<<dim3(512), dim3(256), 0, stream>>>(lengths, pacc, pm, pden, ctxd);
  } else if (ws_size >= ws_need(1)) {
    k_attn<1>   <<<dim3(32), dim3(512), 0, stream>>>(seqs, qwf, qbias, lengths,
                                                     pacc, pm, pden);
    k_reduce<1> <<<dim3(512), dim3(256), 0, stream>>>(lengths, pacc, pm, pden, ctxd);
  } else {
    return;  // scratch too small even for NC=1 (~7 MB) -> fail loudly via validation
  }

  k_vproj  <<<dim3(256),  dim3(256), 0, stream>>>(ipw, ipb, snw, ctxd, abar);
  k_outproj<<<dim3(256),  dim3(256), 0, stream>>>(outw, outb, abar, seqctx);
  k_gate   <<<dim3(256),  dim3(256), 0, stream>>>(gw, gb, context, seqctx, ctxbuf);
  k_gateup <<<dim3(1024), dim3(256), 0, stream>>>(gup, gub, ctxbuf, fnw, gact);
  k_down   <<<dim3(256),  dim3(256), 0, stream>>>(dw, db, gact, ctxbuf, out);
}